// Round 1
// baseline (887.734 us; speedup 1.0000x reference)
//
#include <hip/hip_runtime.h>
#include <math.h>

// ---------------------------------------------------------------------------
// GAT, 3 layers, N=50000, E=800000, H=2 heads, D=64/64/32.
// Strategy: CSR-by-dst built per launch (no atomics in hot loop), then
// block-per-destination-node softmax-aggregate with fused epilogue.
// ---------------------------------------------------------------------------

__global__ __launch_bounds__(256) void hist_k(const int* __restrict__ dst, int E,
                                              int* __restrict__ deg) {
    int e = blockIdx.x * 256 + threadIdx.x;
    if (e < E) atomicAdd(&deg[dst[e]], 1);
}

__global__ __launch_bounds__(512) void scan1_k(const int* __restrict__ deg, int n,
                                               int* __restrict__ incl,
                                               int* __restrict__ bsums) {
    __shared__ int sm[512];
    int t = threadIdx.x;
    int i = blockIdx.x * 512 + t;
    int v = (i < n) ? deg[i] : 0;
    sm[t] = v;
    __syncthreads();
    for (int ofs = 1; ofs < 512; ofs <<= 1) {
        int add = (t >= ofs) ? sm[t - ofs] : 0;
        __syncthreads();
        sm[t] += add;
        __syncthreads();
    }
    if (i < n) incl[i] = sm[t];
    if (t == 511) bsums[blockIdx.x] = sm[511];
}

// exclusive scan of block sums, nb <= 128
__global__ __launch_bounds__(128) void scan2_k(int* __restrict__ bsums, int nb) {
    __shared__ int sm[128];
    int t = threadIdx.x;
    int v = (t < nb) ? bsums[t] : 0;
    sm[t] = v;
    __syncthreads();
    for (int ofs = 1; ofs < 128; ofs <<= 1) {
        int add = (t >= ofs) ? sm[t - ofs] : 0;
        __syncthreads();
        sm[t] += add;
        __syncthreads();
    }
    if (t < nb) bsums[t] = sm[t] - v;  // exclusive
}

__global__ __launch_bounds__(256) void scan3_k(const int* __restrict__ incl,
                                               const int* __restrict__ deg,
                                               const int* __restrict__ bsumsx,
                                               int* __restrict__ offs, int n) {
    int i = blockIdx.x * 256 + threadIdx.x;
    if (i < n) offs[i] = bsumsx[i >> 9] + incl[i] - deg[i];
}

__global__ __launch_bounds__(256) void scatter_k(const int* __restrict__ src,
                                                 const int* __restrict__ dst, int E,
                                                 const int* __restrict__ offs,
                                                 int* __restrict__ cursor,
                                                 int* __restrict__ ssrc) {
    int e = blockIdx.x * 256 + threadIdx.x;
    if (e < E) {
        int d = dst[e];
        int pos = offs[d] + atomicAdd(&cursor[d], 1);
        ssrc[pos] = src[e];
    }
}

// ---------------------------------------------------------------------------
// GEMM: C[n,m] = sum_k A[n,k] * W[k,m].  Block = 256 threads = 4 waves,
// each wave computes one row; x-row staged in LDS (broadcast reads), W
// streamed (<=128KB, L1/L2 resident after warmup).
// ---------------------------------------------------------------------------
template <int K, int M>
__global__ __launch_bounds__(256) void gemm_k(const float* __restrict__ A,
                                              const float* __restrict__ W,
                                              float* __restrict__ C, int nrows) {
    __shared__ float xs[4 * K];
    int row0 = blockIdx.x * 4;
    int tid = threadIdx.x;
    for (int idx = tid; idx < 4 * K; idx += 256) {
        int r = row0 + idx / K;
        xs[idx] = (r < nrows) ? A[(size_t)row0 * K + idx] : 0.f;
    }
    __syncthreads();
    int w = tid >> 6, lane = tid & 63;
    int row = row0 + w;
    if (row >= nrows) return;
    float acc0 = 0.f, acc1 = 0.f;
    const float* xr = xs + w * K;
#pragma unroll 8
    for (int k = 0; k < K; ++k) {
        float xv = xr[k];
        acc0 += xv * W[k * M + lane];
        if (M > 64) acc1 += xv * W[k * M + lane + 64];
    }
    C[(size_t)row * M + lane] = acc0;
    if (M > 64) C[(size_t)row * M + lane + 64] = acc1;
}

// ---------------------------------------------------------------------------
// el/er: dot(h[n,head,:], al[head,:]) etc.  One wave per node.
// ---------------------------------------------------------------------------
__global__ __launch_bounds__(64) void eler64_k(const float* __restrict__ h,
                                               const float* __restrict__ al,
                                               const float* __restrict__ ar,
                                               float* __restrict__ el,
                                               float* __restrict__ er) {
    int node = blockIdx.x;
    int lane = threadIdx.x;
    const float* hr = h + (size_t)node * 128;
    float v0 = hr[lane], v1 = hr[64 + lane];
    float e0 = v0 * al[lane], e1 = v1 * al[64 + lane];
    float r0 = v0 * ar[lane], r1 = v1 * ar[64 + lane];
    for (int ofs = 32; ofs; ofs >>= 1) {
        e0 += __shfl_xor(e0, ofs);
        e1 += __shfl_xor(e1, ofs);
        r0 += __shfl_xor(r0, ofs);
        r1 += __shfl_xor(r1, ofs);
    }
    if (lane == 0) {
        el[node * 2] = e0; el[node * 2 + 1] = e1;
        er[node * 2] = r0; er[node * 2 + 1] = r1;
    }
}

__global__ __launch_bounds__(64) void eler32_k(const float* __restrict__ h,
                                               const float* __restrict__ al,
                                               const float* __restrict__ ar,
                                               float* __restrict__ el,
                                               float* __restrict__ er) {
    int node = blockIdx.x;
    int lane = threadIdx.x;  // 64: lanes 0-31 head0, 32-63 head1
    const float* hr = h + (size_t)node * 64;
    float v = hr[lane];
    float e = v * al[lane];
    float r = v * ar[lane];
    for (int ofs = 16; ofs; ofs >>= 1) {
        e += __shfl_xor(e, ofs, 32);
        r += __shfl_xor(r, ofs, 32);
    }
    if ((lane & 31) == 0) {
        int hh = lane >> 5;
        el[node * 2 + hh] = e;
        er[node * 2 + hh] = r;
    }
}

// ---------------------------------------------------------------------------
// Aggregation: one block per destination node.  2*D threads (head hh = t/D,
// feature d = t%D).  Phase 1: online softmax (m,s) per head with shuffle
// merge.  Phase 2: weighted gather-accumulate of h[src] rows (coalesced).
// Epilogue: +bias, +residual, activation, optional head-mean.
// ---------------------------------------------------------------------------
template <int D, bool MEAN_HEADS>
__global__ __launch_bounds__(2 * D) void agg_k(
    const int* __restrict__ ssrc, const int* __restrict__ offs,
    const int* __restrict__ deg, const float* __restrict__ h,
    const float* __restrict__ el, const float* __restrict__ er,
    const float* __restrict__ bias, const float* __restrict__ res,
    float* __restrict__ out, int act) {
    int node = blockIdx.x;
    int t = threadIdx.x;
    int hh = t / D;
    int d = t % D;
    int off = offs[node];
    int dg = deg[node];
    float ern = er[node * 2 + hh];

    // phase 1: per-thread online softmax over strided edges
    float m = -INFINITY, s = 0.f;
    for (int k = d; k < dg; k += D) {
        int sidx = ssrc[off + k];
        float sc = el[sidx * 2 + hh] + ern;
        sc = sc >= 0.f ? sc : 0.2f * sc;
        float nm = fmaxf(m, sc);
        s = s * __expf(m - nm) + __expf(sc - nm);
        m = nm;
    }
    // butterfly merge within the head's D lanes
    for (int ofs = D >> 1; ofs; ofs >>= 1) {
        float om = __shfl_xor(m, ofs, D);
        float os = __shfl_xor(s, ofs, D);
        float nm = fmaxf(m, om);
        if (nm == -INFINITY) {
            s = 0.f;
        } else {
            s = s * __expf(m - nm) + os * __expf(om - nm);
        }
        m = nm;
    }
    float inv_s = (s > 0.f) ? 1.f / s : 0.f;

    // phase 2: weighted accumulate (all threads walk all edges; h-row reads
    // are coalesced 4B/lane)
    float acc = 0.f;
    for (int k = 0; k < dg; ++k) {
        int sidx = ssrc[off + k];
        float sc = el[sidx * 2 + hh] + ern;
        sc = sc >= 0.f ? sc : 0.2f * sc;
        float w = __expf(sc - m) * inv_s;
        acc += w * h[(size_t)sidx * (2 * D) + t];
    }

    // epilogue
    float v = acc + bias[t];
    if (res) v += res[(size_t)node * (2 * D) + t];
    if (act) v = v > 0.f ? v : __expf(v) - 1.f;
    if (MEAN_HEADS) {
        float other = __shfl_xor(v, D, 2 * D);
        if (hh == 0) out[(size_t)node * D + d] = 0.5f * (v + other);
    } else {
        out[(size_t)node * (2 * D) + t] = v;
    }
}

// ---------------------------------------------------------------------------

extern "C" void kernel_launch(void* const* d_in, const int* in_sizes, int n_in,
                              void* d_out, int out_size, void* d_ws, size_t ws_size,
                              hipStream_t stream) {
    const float* x     = (const float*)d_in[0];
    const int*   esrc  = (const int*)d_in[1];
    const int*   edst  = (const int*)d_in[2];
    const float* W0    = (const float*)d_in[3];
    const float* al0   = (const float*)d_in[4];
    const float* ar0   = (const float*)d_in[5];
    const float* b0    = (const float*)d_in[6];
    const float* W1    = (const float*)d_in[7];
    const float* al1   = (const float*)d_in[8];
    const float* ar1   = (const float*)d_in[9];
    const float* b1    = (const float*)d_in[10];
    const float* W2    = (const float*)d_in[11];
    const float* al2   = (const float*)d_in[12];
    const float* ar2   = (const float*)d_in[13];
    const float* b2    = (const float*)d_in[14];
    const float* Wres2 = (const float*)d_in[15];

    const int N = in_sizes[0] / 256;  // 50000
    const int E = in_sizes[1];        // 800000

    // workspace layout (fp32 elements)
    float* ws = (float*)d_ws;
    float* H  = ws;                        // [N,128]
    float* A  = H + (size_t)N * 128;       // [N,128]
    float* B  = A + (size_t)N * 128;       // [N,128]
    float* el = B + (size_t)N * 128;       // [N,2]
    float* er = el + (size_t)N * 2;        // [N,2]
    int* deg    = (int*)(er + (size_t)N * 2);
    int* offs   = deg + N;
    int* cursor = offs + N;
    int* incl   = cursor + N;
    int* bsums  = incl + N;                // 256 ints
    int* ssrc   = bsums + 256;             // [E]

    // ---- CSR-by-destination build (cheap, per launch) ----
    hipMemsetAsync(deg, 0, (size_t)N * sizeof(int), stream);
    hipMemsetAsync(cursor, 0, (size_t)N * sizeof(int), stream);
    hist_k<<<(E + 255) / 256, 256, 0, stream>>>(edst, E, deg);
    int nb = (N + 511) / 512;  // 98 <= 128
    scan1_k<<<nb, 512, 0, stream>>>(deg, N, incl, bsums);
    scan2_k<<<1, 128, 0, stream>>>(bsums, nb);
    scan3_k<<<(N + 255) / 256, 256, 0, stream>>>(incl, deg, bsums, offs, N);
    scatter_k<<<(E + 255) / 256, 256, 0, stream>>>(esrc, edst, E, offs, cursor, ssrc);

    int gblk = (N + 3) / 4;

    // ---- Layer 0: IN=256 -> [N,2,64], ELU ----
    gemm_k<256, 128><<<gblk, 256, 0, stream>>>(x, W0, H, N);
    eler64_k<<<N, 64, 0, stream>>>(H, al0, ar0, el, er);
    agg_k<64, false><<<N, 128, 0, stream>>>(ssrc, offs, deg, H, el, er, b0,
                                            nullptr, A, 1);

    // ---- Layer 1: 128 -> [N,2,64], identity residual, ELU ----
    gemm_k<128, 128><<<gblk, 256, 0, stream>>>(A, W1, H, N);
    eler64_k<<<N, 64, 0, stream>>>(H, al1, ar1, el, er);
    agg_k<64, false><<<N, 128, 0, stream>>>(ssrc, offs, deg, H, el, er, b1,
                                            A, B, 1);

    // ---- Layer 2: 128 -> [N,2,32], projected residual, head-mean ----
    float* h2   = H;                   // [N,64]
    float* hres = H + (size_t)N * 64;  // [N,64]
    gemm_k<128, 64><<<gblk, 256, 0, stream>>>(B, W2, h2, N);
    gemm_k<128, 64><<<gblk, 256, 0, stream>>>(B, Wres2, hres, N);
    eler32_k<<<N, 64, 0, stream>>>(h2, al2, ar2, el, er);
    agg_k<32, true><<<N, 64, 0, stream>>>(ssrc, offs, deg, h2, el, er, b2,
                                          hres, (float*)d_out, 0);
}

// Round 2
// 618.249 us; speedup vs baseline: 1.4359x; 1.4359x over previous
//
#include <hip/hip_runtime.h>
#include <math.h>

// ---------------------------------------------------------------------------
// GAT, 3 layers, N=50000, E=800000, H=2 heads, D=64/64/32.
// CSR-by-dst built per launch (no atomics in hot loop), register-tiled fp32
// GEMMs (LDS-staged A and W), block-per-destination softmax-aggregate.
// ---------------------------------------------------------------------------

__global__ __launch_bounds__(256) void hist_k(const int* __restrict__ dst, int E,
                                              int* __restrict__ deg) {
    int e = blockIdx.x * 256 + threadIdx.x;
    if (e < E) atomicAdd(&deg[dst[e]], 1);
}

__global__ __launch_bounds__(512) void scan1_k(const int* __restrict__ deg, int n,
                                               int* __restrict__ incl,
                                               int* __restrict__ bsums) {
    __shared__ int sm[512];
    int t = threadIdx.x;
    int i = blockIdx.x * 512 + t;
    int v = (i < n) ? deg[i] : 0;
    sm[t] = v;
    __syncthreads();
    for (int ofs = 1; ofs < 512; ofs <<= 1) {
        int add = (t >= ofs) ? sm[t - ofs] : 0;
        __syncthreads();
        sm[t] += add;
        __syncthreads();
    }
    if (i < n) incl[i] = sm[t];
    if (t == 511) bsums[blockIdx.x] = sm[511];
}

// exclusive scan of block sums, nb <= 128
__global__ __launch_bounds__(128) void scan2_k(int* __restrict__ bsums, int nb) {
    __shared__ int sm[128];
    int t = threadIdx.x;
    int v = (t < nb) ? bsums[t] : 0;
    sm[t] = v;
    __syncthreads();
    for (int ofs = 1; ofs < 128; ofs <<= 1) {
        int add = (t >= ofs) ? sm[t - ofs] : 0;
        __syncthreads();
        sm[t] += add;
        __syncthreads();
    }
    if (t < nb) bsums[t] = sm[t] - v;  // exclusive
}

__global__ __launch_bounds__(256) void scan3_k(const int* __restrict__ incl,
                                               const int* __restrict__ deg,
                                               const int* __restrict__ bsumsx,
                                               int* __restrict__ offs, int n) {
    int i = blockIdx.x * 256 + threadIdx.x;
    if (i < n) offs[i] = bsumsx[i >> 9] + incl[i] - deg[i];
}

__global__ __launch_bounds__(256) void scatter_k(const int* __restrict__ src,
                                                 const int* __restrict__ dst, int E,
                                                 const int* __restrict__ offs,
                                                 int* __restrict__ cursor,
                                                 int* __restrict__ ssrc) {
    int e = blockIdx.x * 256 + threadIdx.x;
    if (e < E) {
        int d = dst[e];
        int pos = offs[d] + atomicAdd(&cursor[d], 1);
        ssrc[pos] = src[e];
    }
}

// ---------------------------------------------------------------------------
// Register-tiled GEMM: C[n,m] = sum_k A[n,k] * W[k,m].
// Block tile: 64 rows x M cols, k-tiled by 64. A and W staged in LDS with
// padded strides (+4 words) so compute-phase reads are <=2-way bank aliased
// (free). 256 threads; each thread owns TM=M/16 rows x 4 cols -> 4*TM FMAs
// per k-step vs ~TM+1 LDS reads: VALU-bound by construction.
// ---------------------------------------------------------------------------
template <int K, int M>
__global__ __launch_bounds__(256) void gemm_t(const float* __restrict__ A,
                                              const float* __restrict__ W,
                                              float* __restrict__ C, int nrows) {
    constexpr int BK = 64, BM = 64;
    constexpr int AP = BK + 4;  // 68: padded A row stride (words)
    constexpr int WP = M + 4;   // padded W row stride (words)
    constexpr int TM = M / 16;  // rows per thread (8 for M=128, 4 for M=64)
    __shared__ float As[BM * AP];  // [row][k]
    __shared__ float Ws[BK * WP];  // [k][m]
    const int tid = threadIdx.x;
    const int row0 = blockIdx.x * BM;
    const int col_t = tid % (M / 4);   // 4-col group
    const int row_t = tid / (M / 4);   // TM-row group

    float4 acc[TM];
#pragma unroll
    for (int i = 0; i < TM; ++i) acc[i] = make_float4(0.f, 0.f, 0.f, 0.f);

    for (int kt = 0; kt < K / BK; ++kt) {
        const int k0 = kt * BK;
        // stage A tile: 64 rows x 64 k = 1024 float4, 4 per thread
#pragma unroll
        for (int t = 0; t < 4; ++t) {
            int idx = tid + t * 256;
            int r = idx >> 4;            // 16 float4 per row
            int kq = (idx & 15) << 2;
            float4 v = make_float4(0.f, 0.f, 0.f, 0.f);
            if (row0 + r < nrows)
                v = *(const float4*)&A[(size_t)(row0 + r) * K + k0 + kq];
            *(float4*)&As[r * AP + kq] = v;
        }
        // stage W tile: 64 k x M
#pragma unroll
        for (int t = 0; t < M / 16; ++t) {
            int idx = tid + t * 256;
            int kk = idx / (M / 4);
            int mq = (idx % (M / 4)) << 2;
            *(float4*)&Ws[kk * WP + mq] =
                *(const float4*)&W[(size_t)(k0 + kk) * M + mq];
        }
        __syncthreads();
#pragma unroll 4
        for (int k = 0; k < BK; ++k) {
            float4 wv = *(const float4*)&Ws[k * WP + (col_t << 2)];
            float av[TM];
#pragma unroll
            for (int i = 0; i < TM; ++i)
                av[i] = As[(row_t * TM + i) * AP + k];
#pragma unroll
            for (int i = 0; i < TM; ++i) {
                acc[i].x += av[i] * wv.x;
                acc[i].y += av[i] * wv.y;
                acc[i].z += av[i] * wv.z;
                acc[i].w += av[i] * wv.w;
            }
        }
        __syncthreads();
    }
#pragma unroll
    for (int i = 0; i < TM; ++i) {
        int row = row0 + row_t * TM + i;
        if (row < nrows)
            *(float4*)&C[(size_t)row * M + (col_t << 2)] = acc[i];
    }
}

// ---------------------------------------------------------------------------
// el/er: dot(h[n,head,:], al[head,:]) etc.  Wave per node, 4 nodes per block.
// ---------------------------------------------------------------------------
__global__ __launch_bounds__(256) void eler64_k(const float* __restrict__ h,
                                                const float* __restrict__ al,
                                                const float* __restrict__ ar,
                                                float* __restrict__ el,
                                                float* __restrict__ er, int n) {
    int node = blockIdx.x * 4 + (threadIdx.x >> 6);
    if (node >= n) return;
    int lane = threadIdx.x & 63;
    const float* hr = h + (size_t)node * 128;
    float v0 = hr[lane], v1 = hr[64 + lane];
    float e0 = v0 * al[lane], e1 = v1 * al[64 + lane];
    float r0 = v0 * ar[lane], r1 = v1 * ar[64 + lane];
    for (int ofs = 32; ofs; ofs >>= 1) {
        e0 += __shfl_xor(e0, ofs);
        e1 += __shfl_xor(e1, ofs);
        r0 += __shfl_xor(r0, ofs);
        r1 += __shfl_xor(r1, ofs);
    }
    if (lane == 0) {
        el[node * 2] = e0; el[node * 2 + 1] = e1;
        er[node * 2] = r0; er[node * 2 + 1] = r1;
    }
}

__global__ __launch_bounds__(256) void eler32_k(const float* __restrict__ h,
                                                const float* __restrict__ al,
                                                const float* __restrict__ ar,
                                                float* __restrict__ el,
                                                float* __restrict__ er, int n) {
    int node = blockIdx.x * 4 + (threadIdx.x >> 6);
    if (node >= n) return;
    int lane = threadIdx.x & 63;  // lanes 0-31 head0, 32-63 head1
    const float* hr = h + (size_t)node * 64;
    float v = hr[lane];
    float e = v * al[lane];
    float r = v * ar[lane];
    for (int ofs = 16; ofs; ofs >>= 1) {
        e += __shfl_xor(e, ofs, 32);
        r += __shfl_xor(r, ofs, 32);
    }
    if ((lane & 31) == 0) {
        int hh = lane >> 5;
        el[node * 2 + hh] = e;
        er[node * 2 + hh] = r;
    }
}

// ---------------------------------------------------------------------------
// Aggregation: one block per destination node.  2*D threads (head hh = t/D,
// feature d = t%D).  Phase 1: online softmax (m,s) per head with shuffle
// merge.  Phase 2: weighted gather-accumulate of h[src] rows (coalesced).
// Epilogue: +bias, +residual, activation, optional head-mean.
// ---------------------------------------------------------------------------
template <int D, bool MEAN_HEADS>
__global__ __launch_bounds__(2 * D) void agg_k(
    const int* __restrict__ ssrc, const int* __restrict__ offs,
    const int* __restrict__ deg, const float* __restrict__ h,
    const float* __restrict__ el, const float* __restrict__ er,
    const float* __restrict__ bias, const float* __restrict__ res,
    float* __restrict__ out, int act) {
    int node = blockIdx.x;
    int t = threadIdx.x;
    int hh = t / D;
    int d = t % D;
    int off = offs[node];
    int dg = deg[node];
    float ern = er[node * 2 + hh];

    // phase 1: per-thread online softmax over strided edges
    float m = -INFINITY, s = 0.f;
    for (int k = d; k < dg; k += D) {
        int sidx = ssrc[off + k];
        float sc = el[sidx * 2 + hh] + ern;
        sc = sc >= 0.f ? sc : 0.2f * sc;
        float nm = fmaxf(m, sc);
        s = s * __expf(m - nm) + __expf(sc - nm);
        m = nm;
    }
    // butterfly merge within the head's D lanes
    for (int ofs = D >> 1; ofs; ofs >>= 1) {
        float om = __shfl_xor(m, ofs, D);
        float os = __shfl_xor(s, ofs, D);
        float nm = fmaxf(m, om);
        if (nm == -INFINITY) {
            s = 0.f;
        } else {
            s = s * __expf(m - nm) + os * __expf(om - nm);
        }
        m = nm;
    }
    float inv_s = (s > 0.f) ? 1.f / s : 0.f;

    // phase 2: weighted accumulate (all threads walk all edges; h-row reads
    // are coalesced 4B/lane)
    float acc = 0.f;
    for (int k = 0; k < dg; ++k) {
        int sidx = ssrc[off + k];
        float sc = el[sidx * 2 + hh] + ern;
        sc = sc >= 0.f ? sc : 0.2f * sc;
        float w = __expf(sc - m) * inv_s;
        acc += w * h[(size_t)sidx * (2 * D) + t];
    }

    // epilogue
    float v = acc + bias[t];
    if (res) v += res[(size_t)node * (2 * D) + t];
    if (act) v = v > 0.f ? v : __expf(v) - 1.f;
    if (MEAN_HEADS) {
        float other = __shfl_xor(v, D, 2 * D);
        if (hh == 0) out[(size_t)node * D + d] = 0.5f * (v + other);
    } else {
        out[(size_t)node * (2 * D) + t] = v;
    }
}

// ---------------------------------------------------------------------------

extern "C" void kernel_launch(void* const* d_in, const int* in_sizes, int n_in,
                              void* d_out, int out_size, void* d_ws, size_t ws_size,
                              hipStream_t stream) {
    const float* x     = (const float*)d_in[0];
    const int*   esrc  = (const int*)d_in[1];
    const int*   edst  = (const int*)d_in[2];
    const float* W0    = (const float*)d_in[3];
    const float* al0   = (const float*)d_in[4];
    const float* ar0   = (const float*)d_in[5];
    const float* b0    = (const float*)d_in[6];
    const float* W1    = (const float*)d_in[7];
    const float* al1   = (const float*)d_in[8];
    const float* ar1   = (const float*)d_in[9];
    const float* b1    = (const float*)d_in[10];
    const float* W2    = (const float*)d_in[11];
    const float* al2   = (const float*)d_in[12];
    const float* ar2   = (const float*)d_in[13];
    const float* b2    = (const float*)d_in[14];
    const float* Wres2 = (const float*)d_in[15];

    const int N = in_sizes[0] / 256;  // 50000
    const int E = in_sizes[1];        // 800000

    // workspace layout (fp32 elements)
    float* ws = (float*)d_ws;
    float* H  = ws;                        // [N,128]
    float* A  = H + (size_t)N * 128;       // [N,128]
    float* B  = A + (size_t)N * 128;       // [N,128]
    float* el = B + (size_t)N * 128;       // [N,2]
    float* er = el + (size_t)N * 2;        // [N,2]
    int* deg    = (int*)(er + (size_t)N * 2);
    int* offs   = deg + N;
    int* cursor = offs + N;
    int* incl   = cursor + N;
    int* bsums  = incl + N;                // 256 ints
    int* ssrc   = bsums + 256;             // [E]

    // ---- CSR-by-destination build (cheap, per launch) ----
    hipMemsetAsync(deg, 0, (size_t)N * sizeof(int), stream);
    hipMemsetAsync(cursor, 0, (size_t)N * sizeof(int), stream);
    hist_k<<<(E + 255) / 256, 256, 0, stream>>>(edst, E, deg);
    int nb = (N + 511) / 512;  // 98 <= 128
    scan1_k<<<nb, 512, 0, stream>>>(deg, N, incl, bsums);
    scan2_k<<<1, 128, 0, stream>>>(bsums, nb);
    scan3_k<<<(N + 255) / 256, 256, 0, stream>>>(incl, deg, bsums, offs, N);
    scatter_k<<<(E + 255) / 256, 256, 0, stream>>>(esrc, edst, E, offs, cursor, ssrc);

    int gblk = (N + 63) / 64;   // 782
    int eblk = (N + 3) / 4;

    // ---- Layer 0: IN=256 -> [N,2,64], ELU ----
    gemm_t<256, 128><<<gblk, 256, 0, stream>>>(x, W0, H, N);
    eler64_k<<<eblk, 256, 0, stream>>>(H, al0, ar0, el, er, N);
    agg_k<64, false><<<N, 128, 0, stream>>>(ssrc, offs, deg, H, el, er, b0,
                                            nullptr, A, 1);

    // ---- Layer 1: 128 -> [N,2,64], identity residual, ELU ----
    gemm_t<128, 128><<<gblk, 256, 0, stream>>>(A, W1, H, N);
    eler64_k<<<eblk, 256, 0, stream>>>(H, al1, ar1, el, er, N);
    agg_k<64, false><<<N, 128, 0, stream>>>(ssrc, offs, deg, H, el, er, b1,
                                            A, B, 1);

    // ---- Layer 2: 128 -> [N,2,32], projected residual, head-mean ----
    float* h2   = H;                   // [N,64]
    float* hres = H + (size_t)N * 64;  // [N,64]
    gemm_t<128, 64><<<gblk, 256, 0, stream>>>(B, W2, h2, N);
    gemm_t<128, 64><<<gblk, 256, 0, stream>>>(B, Wres2, hres, N);
    eler32_k<<<eblk, 256, 0, stream>>>(h2, al2, ar2, el, er, N);
    agg_k<32, true><<<N, 64, 0, stream>>>(ssrc, offs, deg, h2, el, er, b2,
                                          hres, (float*)d_out, 0);
}

// Round 3
// 611.380 us; speedup vs baseline: 1.4520x; 1.0112x over previous
//
#include <hip/hip_runtime.h>
#include <math.h>

// ---------------------------------------------------------------------------
// GAT, 3 layers, N=50000, E=800000, H=2 heads, D=64/64/32.
// CSR-by-dst built per launch; register-tiled fp32 GEMM with fused el/er
// epilogue; subwave-per-(node,head) softmax-aggregate with shuffle-broadcast
// edge weights.
// ---------------------------------------------------------------------------

__global__ __launch_bounds__(256) void hist_k(const int* __restrict__ dst, int E,
                                              int* __restrict__ deg) {
    int e = blockIdx.x * 256 + threadIdx.x;
    if (e < E) atomicAdd(&deg[dst[e]], 1);
}

__global__ __launch_bounds__(512) void scan1_k(const int* __restrict__ deg, int n,
                                               int* __restrict__ incl,
                                               int* __restrict__ bsums) {
    __shared__ int sm[512];
    int t = threadIdx.x;
    int i = blockIdx.x * 512 + t;
    int v = (i < n) ? deg[i] : 0;
    sm[t] = v;
    __syncthreads();
    for (int ofs = 1; ofs < 512; ofs <<= 1) {
        int add = (t >= ofs) ? sm[t - ofs] : 0;
        __syncthreads();
        sm[t] += add;
        __syncthreads();
    }
    if (i < n) incl[i] = sm[t];
    if (t == 511) bsums[blockIdx.x] = sm[511];
}

// exclusive scan of block sums, nb <= 128
__global__ __launch_bounds__(128) void scan2_k(int* __restrict__ bsums, int nb) {
    __shared__ int sm[128];
    int t = threadIdx.x;
    int v = (t < nb) ? bsums[t] : 0;
    sm[t] = v;
    __syncthreads();
    for (int ofs = 1; ofs < 128; ofs <<= 1) {
        int add = (t >= ofs) ? sm[t - ofs] : 0;
        __syncthreads();
        sm[t] += add;
        __syncthreads();
    }
    if (t < nb) bsums[t] = sm[t] - v;  // exclusive
}

__global__ __launch_bounds__(256) void scan3_k(const int* __restrict__ incl,
                                               const int* __restrict__ deg,
                                               const int* __restrict__ bsumsx,
                                               int* __restrict__ offs, int n) {
    int i = blockIdx.x * 256 + threadIdx.x;
    if (i < n) offs[i] = bsumsx[i >> 9] + incl[i] - deg[i];
}

__global__ __launch_bounds__(256) void scatter_k(const int* __restrict__ src,
                                                 const int* __restrict__ dst, int E,
                                                 const int* __restrict__ offs,
                                                 int* __restrict__ cursor,
                                                 int* __restrict__ ssrc) {
    int e = blockIdx.x * 256 + threadIdx.x;
    if (e < E) {
        int d = dst[e];
        int pos = offs[d] + atomicAdd(&cursor[d], 1);
        ssrc[pos] = src[e];
    }
}

// ---------------------------------------------------------------------------
// Register-tiled GEMM: C[n,m] = sum_k A[n,k] * W[k,m], plus (optional) fused
// el/er epilogue: el[n,h] = sum_d C[n, h*D+d]*al[h*D+d] (al flat length M).
// Block tile 64 x M, k-tiled by 64; A/W staged in LDS (padded strides).
// ---------------------------------------------------------------------------
template <int K, int M>
__global__ __launch_bounds__(256) void gemm_t(const float* __restrict__ A,
                                              const float* __restrict__ W,
                                              float* __restrict__ C, int nrows,
                                              const float* __restrict__ al,
                                              const float* __restrict__ ar,
                                              float* __restrict__ el,
                                              float* __restrict__ er) {
    constexpr int BK = 64, BM = 64;
    constexpr int AP = BK + 4;  // padded A row stride (words)
    constexpr int WP = M + 4;   // padded W row stride (words)
    constexpr int TM = M / 16;  // rows per thread
    __shared__ float As[BM * AP];  // [row][k]
    __shared__ float Ws[BK * WP];  // [k][m]
    const int tid = threadIdx.x;
    const int row0 = blockIdx.x * BM;
    const int col_t = tid % (M / 4);   // 4-col group
    const int row_t = tid / (M / 4);   // TM-row group

    float4 acc[TM];
#pragma unroll
    for (int i = 0; i < TM; ++i) acc[i] = make_float4(0.f, 0.f, 0.f, 0.f);

    for (int kt = 0; kt < K / BK; ++kt) {
        const int k0 = kt * BK;
#pragma unroll
        for (int t = 0; t < 4; ++t) {
            int idx = tid + t * 256;
            int r = idx >> 4;            // 16 float4 per row
            int kq = (idx & 15) << 2;
            float4 v = make_float4(0.f, 0.f, 0.f, 0.f);
            if (row0 + r < nrows)
                v = *(const float4*)&A[(size_t)(row0 + r) * K + k0 + kq];
            *(float4*)&As[r * AP + kq] = v;
        }
#pragma unroll
        for (int t = 0; t < M / 16; ++t) {
            int idx = tid + t * 256;
            int kk = idx / (M / 4);
            int mq = (idx % (M / 4)) << 2;
            *(float4*)&Ws[kk * WP + mq] =
                *(const float4*)&W[(size_t)(k0 + kk) * M + mq];
        }
        __syncthreads();
#pragma unroll 4
        for (int k = 0; k < BK; ++k) {
            float4 wv = *(const float4*)&Ws[k * WP + (col_t << 2)];
            float av[TM];
#pragma unroll
            for (int i = 0; i < TM; ++i)
                av[i] = As[(row_t * TM + i) * AP + k];
#pragma unroll
            for (int i = 0; i < TM; ++i) {
                acc[i].x += av[i] * wv.x;
                acc[i].y += av[i] * wv.y;
                acc[i].z += av[i] * wv.z;
                acc[i].w += av[i] * wv.w;
            }
        }
        __syncthreads();
    }
    const int col4 = col_t << 2;
#pragma unroll
    for (int i = 0; i < TM; ++i) {
        int row = row0 + row_t * TM + i;
        if (row < nrows)
            *(float4*)&C[(size_t)row * M + col4] = acc[i];
    }
    // fused el/er epilogue (skipped when al==nullptr, e.g. residual gemm)
    if (al != nullptr) {
        constexpr int NCG = M / 4;  // col groups
        constexpr int PS = NCG + 1; // padded stride: avoid pow2 bank stride
        float* pel = As;            // reuse LDS (post final syncthreads)
        float* per_ = Ws;
        float a0 = al[col4], a1 = al[col4 + 1], a2 = al[col4 + 2], a3 = al[col4 + 3];
        float r0 = ar[col4], r1 = ar[col4 + 1], r2 = ar[col4 + 2], r3 = ar[col4 + 3];
#pragma unroll
        for (int i = 0; i < TM; ++i) {
            int lr = row_t * TM + i;
            pel[lr * PS + col_t] =
                acc[i].x * a0 + acc[i].y * a1 + acc[i].z * a2 + acc[i].w * a3;
            per_[lr * PS + col_t] =
                acc[i].x * r0 + acc[i].y * r1 + acc[i].z * r2 + acc[i].w * r3;
        }
        __syncthreads();
        // 64 rows x {head0,head1} x {el,er} = 256 outputs, one per thread
        int row = tid >> 2;
        int hh = tid & 1;
        int iser = (tid >> 1) & 1;
        const float* p = iser ? per_ : pel;
        float sum = 0.f;
#pragma unroll
        for (int g = 0; g < NCG / 2; ++g)
            sum += p[row * PS + hh * (NCG / 2) + g];
        int grow = row0 + row;
        if (grow < nrows) {
            float* dstp = iser ? er : el;
            dstp[grow * 2 + hh] = sum;
        }
    }
}

// ---------------------------------------------------------------------------
// Aggregation: one D-lane subwave per (node, head).  Phase 1: lane k scores
// edge k (chunked by D), online-softmax reduce via shuffles.  Phase 2: each
// edge's weight+src broadcast by shuffle; coalesced 4B/lane gather of the
// head's h row; fused bias/residual/activation/head-mean epilogue.
// ---------------------------------------------------------------------------
template <int D, bool MEAN_HEADS>
__global__ __launch_bounds__(256) void agg_w(
    const int* __restrict__ ssrc, const int* __restrict__ offs,
    const int* __restrict__ deg, const float* __restrict__ h,
    const float* __restrict__ el, const float* __restrict__ er,
    const float* __restrict__ bias, const float* __restrict__ res,
    float* __restrict__ out, int act, int n) {
    static_assert(!MEAN_HEADS || D <= 32, "head-mean shuffle needs 2D<=64");
    const int tid = threadIdx.x;
    const int sub = tid / D;        // subwave id (2 per node)
    const int fl = tid % D;         // feature lane
    const int node = blockIdx.x * (128 / D) + (sub >> 1);
    const int hh = sub & 1;
    if (node >= n) return;
    const int off = offs[node];
    const int dg = deg[node];
    const float ern = er[node * 2 + hh];

    // phase 1: per-lane online softmax over its edges; keep first chunk's
    // score/src in registers to avoid a reload in phase 2.
    float m = -INFINITY, s = 0.f;
    float sc0 = 0.f;
    int sidx0 = 0;
    for (int k = fl; k < dg; k += D) {
        int sidx = ssrc[off + k];
        float sc = el[sidx * 2 + hh] + ern;
        sc = sc >= 0.f ? sc : 0.2f * sc;
        if (k == fl) { sc0 = sc; sidx0 = sidx; }
        float nm = fmaxf(m, sc);
        s = s * __expf(m - nm) + __expf(sc - nm);
        m = nm;
    }
    for (int o = D >> 1; o; o >>= 1) {
        float om = __shfl_xor(m, o, D);
        float os = __shfl_xor(s, o, D);
        float nm = fmaxf(m, om);
        s = (nm == -INFINITY) ? 0.f
                              : s * __expf(m - nm) + os * __expf(om - nm);
        m = nm;
    }
    float inv_s = (s > 0.f) ? 1.f / s : 0.f;

    // phase 2: shuffle-broadcast weight+src per edge, coalesced gather
    float acc = 0.f;
    const float* hb = h + hh * D + fl;
    for (int c0 = 0; c0 < dg; c0 += D) {
        float w;
        int sidx;
        if (c0 == 0) {
            w = (fl < dg) ? __expf(sc0 - m) * inv_s : 0.f;
            sidx = sidx0;
        } else {
            int k = c0 + fl;
            if (k < dg) {
                sidx = ssrc[off + k];
                float sc = el[sidx * 2 + hh] + ern;
                sc = sc >= 0.f ? sc : 0.2f * sc;
                w = __expf(sc - m) * inv_s;
            } else {
                w = 0.f;
                sidx = 0;
            }
        }
        int cnt = min(D, dg - c0);
#pragma unroll 4
        for (int j = 0; j < cnt; ++j) {
            float wj = __shfl(w, j, D);
            int sj = __shfl(sidx, j, D);
            acc += wj * hb[(size_t)sj * (2 * D)];
        }
    }

    // epilogue
    float v = acc + bias[hh * D + fl];
    if (res) v += res[(size_t)node * (2 * D) + hh * D + fl];
    if (act) v = v > 0.f ? v : __expf(v) - 1.f;
    if (MEAN_HEADS) {
        float other = __shfl_xor(v, D, 2 * D);  // swap the two head subwaves
        if (hh == 0) out[(size_t)node * D + fl] = 0.5f * (v + other);
    } else {
        out[(size_t)node * (2 * D) + hh * D + fl] = v;
    }
}

// ---------------------------------------------------------------------------

extern "C" void kernel_launch(void* const* d_in, const int* in_sizes, int n_in,
                              void* d_out, int out_size, void* d_ws, size_t ws_size,
                              hipStream_t stream) {
    const float* x     = (const float*)d_in[0];
    const int*   esrc  = (const int*)d_in[1];
    const int*   edst  = (const int*)d_in[2];
    const float* W0    = (const float*)d_in[3];
    const float* al0   = (const float*)d_in[4];
    const float* ar0   = (const float*)d_in[5];
    const float* b0    = (const float*)d_in[6];
    const float* W1    = (const float*)d_in[7];
    const float* al1   = (const float*)d_in[8];
    const float* ar1   = (const float*)d_in[9];
    const float* b1    = (const float*)d_in[10];
    const float* W2    = (const float*)d_in[11];
    const float* al2   = (const float*)d_in[12];
    const float* ar2   = (const float*)d_in[13];
    const float* b2    = (const float*)d_in[14];
    const float* Wres2 = (const float*)d_in[15];

    const int N = in_sizes[0] / 256;  // 50000
    const int E = in_sizes[1];        // 800000

    // workspace layout (fp32 elements)
    float* ws = (float*)d_ws;
    float* H  = ws;                        // [N,128]
    float* A  = H + (size_t)N * 128;       // [N,128]
    float* B  = A + (size_t)N * 128;       // [N,128]
    float* el = B + (size_t)N * 128;       // [N,2]
    float* er = el + (size_t)N * 2;        // [N,2]
    int* deg    = (int*)(er + (size_t)N * 2);
    int* offs   = deg + N;
    int* cursor = offs + N;
    int* incl   = cursor + N;
    int* bsums  = incl + N;                // 256 ints
    int* ssrc   = bsums + 256;             // [E]

    // ---- CSR-by-destination build ----
    hipMemsetAsync(deg, 0, (size_t)N * sizeof(int), stream);
    hipMemsetAsync(cursor, 0, (size_t)N * sizeof(int), stream);
    hist_k<<<(E + 255) / 256, 256, 0, stream>>>(edst, E, deg);
    int nb = (N + 511) / 512;  // 98 <= 128
    scan1_k<<<nb, 512, 0, stream>>>(deg, N, incl, bsums);
    scan2_k<<<1, 128, 0, stream>>>(bsums, nb);
    scan3_k<<<(N + 255) / 256, 256, 0, stream>>>(incl, deg, bsums, offs, N);
    scatter_k<<<(E + 255) / 256, 256, 0, stream>>>(esrc, edst, E, offs, cursor, ssrc);

    int gblk = (N + 63) / 64;   // 782
    int ablk64 = (N + 1) / 2;   // 2 nodes/block for D=64
    int ablk32 = (N + 3) / 4;   // 4 nodes/block for D=32

    // ---- Layer 0: IN=256 -> [N,2,64], ELU ----
    gemm_t<256, 128><<<gblk, 256, 0, stream>>>(x, W0, H, N, al0, ar0, el, er);
    agg_w<64, false><<<ablk64, 256, 0, stream>>>(ssrc, offs, deg, H, el, er, b0,
                                                 nullptr, A, 1, N);

    // ---- Layer 1: 128 -> [N,2,64], identity residual, ELU ----
    gemm_t<128, 128><<<gblk, 256, 0, stream>>>(A, W1, H, N, al1, ar1, el, er);
    agg_w<64, false><<<ablk64, 256, 0, stream>>>(ssrc, offs, deg, H, el, er, b1,
                                                 A, B, 1, N);

    // ---- Layer 2: 128 -> [N,2,32], projected residual, head-mean ----
    float* h2   = H;                   // [N,64]
    float* hres = H + (size_t)N * 64;  // [N,64]
    gemm_t<128, 64><<<gblk, 256, 0, stream>>>(B, W2, h2, N, al2, ar2, el, er);
    gemm_t<128, 64><<<gblk, 256, 0, stream>>>(B, Wres2, hres, N, nullptr, nullptr,
                                              nullptr, nullptr);
    agg_w<32, true><<<ablk32, 256, 0, stream>>>(ssrc, offs, deg, h2, el, er, b2,
                                                hres, (float*)d_out, 0, N);
}

// Round 4
// 489.511 us; speedup vs baseline: 1.8135x; 1.2490x over previous
//
#include <hip/hip_runtime.h>
#include <math.h>

// ---------------------------------------------------------------------------
// GAT, 3 layers, N=50000, E=800000, H=2 heads, D=64/64/32.
// CSR-by-dst built per launch; register-tiled fp32 GEMM with fused el/er
// epilogue; wave-per-node aggregate: float4 lanes cover 2 (D=64) or 4 (D=32)
// full edge rows per wave-load, weights broadcast via bpermute.
// ---------------------------------------------------------------------------

__global__ __launch_bounds__(256) void hist_k(const int* __restrict__ dst, int E,
                                              int* __restrict__ deg) {
    int e = blockIdx.x * 256 + threadIdx.x;
    if (e < E) atomicAdd(&deg[dst[e]], 1);
}

__global__ __launch_bounds__(512) void scan1_k(const int* __restrict__ deg, int n,
                                               int* __restrict__ incl,
                                               int* __restrict__ bsums) {
    __shared__ int sm[512];
    int t = threadIdx.x;
    int i = blockIdx.x * 512 + t;
    int v = (i < n) ? deg[i] : 0;
    sm[t] = v;
    __syncthreads();
    for (int ofs = 1; ofs < 512; ofs <<= 1) {
        int add = (t >= ofs) ? sm[t - ofs] : 0;
        __syncthreads();
        sm[t] += add;
        __syncthreads();
    }
    if (i < n) incl[i] = sm[t];
    if (t == 511) bsums[blockIdx.x] = sm[511];
}

// exclusive scan of block sums, nb <= 128
__global__ __launch_bounds__(128) void scan2_k(int* __restrict__ bsums, int nb) {
    __shared__ int sm[128];
    int t = threadIdx.x;
    int v = (t < nb) ? bsums[t] : 0;
    sm[t] = v;
    __syncthreads();
    for (int ofs = 1; ofs < 128; ofs <<= 1) {
        int add = (t >= ofs) ? sm[t - ofs] : 0;
        __syncthreads();
        sm[t] += add;
        __syncthreads();
    }
    if (t < nb) bsums[t] = sm[t] - v;  // exclusive
}

__global__ __launch_bounds__(256) void scan3_k(const int* __restrict__ incl,
                                               const int* __restrict__ deg,
                                               const int* __restrict__ bsumsx,
                                               int* __restrict__ offs, int n) {
    int i = blockIdx.x * 256 + threadIdx.x;
    if (i < n) offs[i] = bsumsx[i >> 9] + incl[i] - deg[i];
}

__global__ __launch_bounds__(256) void scatter_k(const int* __restrict__ src,
                                                 const int* __restrict__ dst, int E,
                                                 const int* __restrict__ offs,
                                                 int* __restrict__ cursor,
                                                 int* __restrict__ ssrc) {
    int e = blockIdx.x * 256 + threadIdx.x;
    if (e < E) {
        int d = dst[e];
        int pos = offs[d] + atomicAdd(&cursor[d], 1);
        ssrc[pos] = src[e];
    }
}

// ---------------------------------------------------------------------------
// Register-tiled GEMM: C[n,m] = sum_k A[n,k] * W[k,m], plus (optional) fused
// el/er epilogue: el[n,h] = sum_d C[n, h*D+d]*al[h*D+d] (al flat length M).
// Block tile 64 x M, k-tiled by 64; A/W staged in LDS (padded strides).
// ---------------------------------------------------------------------------
template <int K, int M>
__global__ __launch_bounds__(256) void gemm_t(const float* __restrict__ A,
                                              const float* __restrict__ W,
                                              float* __restrict__ C, int nrows,
                                              const float* __restrict__ al,
                                              const float* __restrict__ ar,
                                              float* __restrict__ el,
                                              float* __restrict__ er) {
    constexpr int BK = 64, BM = 64;
    constexpr int AP = BK + 4;  // padded A row stride (words)
    constexpr int WP = M + 4;   // padded W row stride (words)
    constexpr int TM = M / 16;  // rows per thread
    __shared__ float As[BM * AP];  // [row][k]
    __shared__ float Ws[BK * WP];  // [k][m]
    const int tid = threadIdx.x;
    const int row0 = blockIdx.x * BM;
    const int col_t = tid % (M / 4);   // 4-col group
    const int row_t = tid / (M / 4);   // TM-row group

    float4 acc[TM];
#pragma unroll
    for (int i = 0; i < TM; ++i) acc[i] = make_float4(0.f, 0.f, 0.f, 0.f);

    for (int kt = 0; kt < K / BK; ++kt) {
        const int k0 = kt * BK;
#pragma unroll
        for (int t = 0; t < 4; ++t) {
            int idx = tid + t * 256;
            int r = idx >> 4;            // 16 float4 per row
            int kq = (idx & 15) << 2;
            float4 v = make_float4(0.f, 0.f, 0.f, 0.f);
            if (row0 + r < nrows)
                v = *(const float4*)&A[(size_t)(row0 + r) * K + k0 + kq];
            *(float4*)&As[r * AP + kq] = v;
        }
#pragma unroll
        for (int t = 0; t < M / 16; ++t) {
            int idx = tid + t * 256;
            int kk = idx / (M / 4);
            int mq = (idx % (M / 4)) << 2;
            *(float4*)&Ws[kk * WP + mq] =
                *(const float4*)&W[(size_t)(k0 + kk) * M + mq];
        }
        __syncthreads();
#pragma unroll 4
        for (int k = 0; k < BK; ++k) {
            float4 wv = *(const float4*)&Ws[k * WP + (col_t << 2)];
            float av[TM];
#pragma unroll
            for (int i = 0; i < TM; ++i)
                av[i] = As[(row_t * TM + i) * AP + k];
#pragma unroll
            for (int i = 0; i < TM; ++i) {
                acc[i].x += av[i] * wv.x;
                acc[i].y += av[i] * wv.y;
                acc[i].z += av[i] * wv.z;
                acc[i].w += av[i] * wv.w;
            }
        }
        __syncthreads();
    }
    const int col4 = col_t << 2;
#pragma unroll
    for (int i = 0; i < TM; ++i) {
        int row = row0 + row_t * TM + i;
        if (row < nrows)
            *(float4*)&C[(size_t)row * M + col4] = acc[i];
    }
    // fused el/er epilogue (skipped when al==nullptr, e.g. residual gemm)
    if (al != nullptr) {
        constexpr int NCG = M / 4;  // col groups
        constexpr int PS = NCG + 1; // padded stride
        float* pel = As;            // reuse LDS (post final syncthreads)
        float* per_ = Ws;
        float a0 = al[col4], a1 = al[col4 + 1], a2 = al[col4 + 2], a3 = al[col4 + 3];
        float r0 = ar[col4], r1 = ar[col4 + 1], r2 = ar[col4 + 2], r3 = ar[col4 + 3];
#pragma unroll
        for (int i = 0; i < TM; ++i) {
            int lr = row_t * TM + i;
            pel[lr * PS + col_t] =
                acc[i].x * a0 + acc[i].y * a1 + acc[i].z * a2 + acc[i].w * a3;
            per_[lr * PS + col_t] =
                acc[i].x * r0 + acc[i].y * r1 + acc[i].z * r2 + acc[i].w * r3;
        }
        __syncthreads();
        // 64 rows x {head0,head1} x {el,er} = 256 outputs, one per thread
        int row = tid >> 2;
        int hh = tid & 1;
        int iser = (tid >> 1) & 1;
        const float* p = iser ? per_ : pel;
        float sum = 0.f;
#pragma unroll
        for (int g = 0; g < NCG / 2; ++g)
            sum += p[row * PS + hh * (NCG / 2) + g];
        int grow = row0 + row;
        if (grow < nrows) {
            float* dstp = iser ? er : el;
            dstp[grow * 2 + hh] = sum;
        }
    }
}

// ---------------------------------------------------------------------------
// Aggregation: one 64-lane wave per node, both heads.  Row = 2*D floats.
// Lane = (edge-slot es, float4-chunk c): ES = 64/(R/4) edges per wave-load
// (2 for D=64, 4 for D=32), 1 KB per load instruction.
// Phase 1: lane k scores edge k (both heads, one float2 el load), 64-wide
// online-softmax butterfly.  Phase 2: per ES-group of edges, broadcast
// (src, w0, w1) via 3 bpermutes, one float4 gather + 4 FMA per lane.
// Edge-slot partials combined by shfl_xor; fused epilogue.
// ---------------------------------------------------------------------------
template <int D, bool MEAN_HEADS>
__global__ __launch_bounds__(256) void agg_v(
    const int* __restrict__ ssrc, const int* __restrict__ offs,
    const int* __restrict__ deg, const float* __restrict__ h,
    const float* __restrict__ el, const float* __restrict__ er,
    const float* __restrict__ bias, const float* __restrict__ res,
    float* __restrict__ out, int act, int n) {
    constexpr int R = 2 * D;       // row length (floats)
    constexpr int CH = R / 4;      // float4 chunks per row (32 / 16)
    constexpr int ES = 64 / CH;    // edge slots per wave (2 / 4)
    const int wid = threadIdx.x >> 6;
    const int lane = threadIdx.x & 63;
    const int node = blockIdx.x * 4 + wid;
    if (node >= n) return;
    const int off = offs[node];
    const int dg = deg[node];
    const float2 ern = *(const float2*)&er[node * 2];

    // ---- phase 1: per-lane (lane <-> edge) online softmax, both heads ----
    float m0 = -INFINITY, s0 = 0.f, m1 = -INFINITY, s1 = 0.f;
    float sc0_r = 0.f, sc1_r = 0.f;
    int sidx_r = 0;
    for (int k = lane; k < dg; k += 64) {
        int sidx = ssrc[off + k];
        float2 elv = *(const float2*)&el[sidx * 2];
        float a = elv.x + ern.x; a = a >= 0.f ? a : 0.2f * a;
        float b = elv.y + ern.y; b = b >= 0.f ? b : 0.2f * b;
        if (k == lane) { sc0_r = a; sc1_r = b; sidx_r = sidx; }
        float nm0 = fmaxf(m0, a);
        s0 = s0 * __expf(m0 - nm0) + __expf(a - nm0); m0 = nm0;
        float nm1 = fmaxf(m1, b);
        s1 = s1 * __expf(m1 - nm1) + __expf(b - nm1); m1 = nm1;
    }
    for (int o = 32; o; o >>= 1) {
        float om = __shfl_xor(m0, o), os = __shfl_xor(s0, o);
        float nm = fmaxf(m0, om);
        s0 = (nm == -INFINITY) ? 0.f : s0 * __expf(m0 - nm) + os * __expf(om - nm);
        m0 = nm;
        om = __shfl_xor(m1, o); os = __shfl_xor(s1, o);
        nm = fmaxf(m1, om);
        s1 = (nm == -INFINITY) ? 0.f : s1 * __expf(m1 - nm) + os * __expf(om - nm);
        m1 = nm;
    }
    const float is0 = (s0 > 0.f) ? 1.f / s0 : 0.f;
    const float is1 = (s1 > 0.f) ? 1.f / s1 : 0.f;

    // ---- phase 2: gather-accumulate, ES edges per iteration ----
    const int c = lane & (CH - 1);       // chunk within row
    const int es = lane / CH;            // edge slot
    const int hh_l = (c * 4) / D;        // head this chunk belongs to
    const float4* __restrict__ hp = (const float4*)h;
    float4 acc = make_float4(0.f, 0.f, 0.f, 0.f);

    for (int c0 = 0; c0 < dg; c0 += 64) {
        float w0, w1;
        int sidx;
        if (c0 == 0) {
            sidx = sidx_r;
            w0 = (lane < dg) ? __expf(sc0_r - m0) * is0 : 0.f;
            w1 = (lane < dg) ? __expf(sc1_r - m1) * is1 : 0.f;
        } else {
            int k = c0 + lane;
            if (k < dg) {
                sidx = ssrc[off + k];
                float2 elv = *(const float2*)&el[sidx * 2];
                float a = elv.x + ern.x; a = a >= 0.f ? a : 0.2f * a;
                float b = elv.y + ern.y; b = b >= 0.f ? b : 0.2f * b;
                w0 = __expf(a - m0) * is0;
                w1 = __expf(b - m1) * is1;
            } else {
                sidx = 0; w0 = 0.f; w1 = 0.f;
            }
        }
        const int cnt = min(64, dg - c0);
#pragma unroll 2
        for (int p = 0; p < cnt; p += ES) {
            int j = p + es;
            int jc = (j < cnt) ? j : 0;
            int sj = __shfl(sidx, jc);
            float w0j = __shfl(w0, jc);
            float w1j = __shfl(w1, jc);
            float wj = (j < cnt) ? (hh_l ? w1j : w0j) : 0.f;
            float4 hv = hp[(size_t)sj * CH + c];
            acc.x += wj * hv.x;
            acc.y += wj * hv.y;
            acc.z += wj * hv.z;
            acc.w += wj * hv.w;
        }
    }

    // combine edge-slot partials (all lanes end up with the full sum)
#pragma unroll
    for (int o = CH; o < 64; o <<= 1) {
        acc.x += __shfl_xor(acc.x, o);
        acc.y += __shfl_xor(acc.y, o);
        acc.z += __shfl_xor(acc.z, o);
        acc.w += __shfl_xor(acc.w, o);
    }

    // ---- epilogue (all lanes execute; stores gated) ----
    const int f = c * 4;
    float4 bv = *(const float4*)&bias[f];
    float4 v = make_float4(acc.x + bv.x, acc.y + bv.y, acc.z + bv.z, acc.w + bv.w);
    if (res) {
        float4 rv = *(const float4*)&res[(size_t)node * R + f];
        v.x += rv.x; v.y += rv.y; v.z += rv.z; v.w += rv.w;
    }
    if (act) {
        v.x = v.x > 0.f ? v.x : __expf(v.x) - 1.f;
        v.y = v.y > 0.f ? v.y : __expf(v.y) - 1.f;
        v.z = v.z > 0.f ? v.z : __expf(v.z) - 1.f;
        v.w = v.w > 0.f ? v.w : __expf(v.w) - 1.f;
    }
    if (MEAN_HEADS) {
        // head1 chunk sits D/4 chunks above head0; xor within the CH group
        float4 o4;
        o4.x = __shfl_xor(v.x, D / 4);
        o4.y = __shfl_xor(v.y, D / 4);
        o4.z = __shfl_xor(v.z, D / 4);
        o4.w = __shfl_xor(v.w, D / 4);
        if (es == 0 && c < D / 4) {
            float4 mv = make_float4(0.5f * (v.x + o4.x), 0.5f * (v.y + o4.y),
                                    0.5f * (v.z + o4.z), 0.5f * (v.w + o4.w));
            *(float4*)&out[(size_t)node * D + f] = mv;
        }
    } else {
        if (es == 0)
            *(float4*)&out[(size_t)node * R + f] = v;
    }
}

// ---------------------------------------------------------------------------

extern "C" void kernel_launch(void* const* d_in, const int* in_sizes, int n_in,
                              void* d_out, int out_size, void* d_ws, size_t ws_size,
                              hipStream_t stream) {
    const float* x     = (const float*)d_in[0];
    const int*   esrc  = (const int*)d_in[1];
    const int*   edst  = (const int*)d_in[2];
    const float* W0    = (const float*)d_in[3];
    const float* al0   = (const float*)d_in[4];
    const float* ar0   = (const float*)d_in[5];
    const float* b0    = (const float*)d_in[6];
    const float* W1    = (const float*)d_in[7];
    const float* al1   = (const float*)d_in[8];
    const float* ar1   = (const float*)d_in[9];
    const float* b1    = (const float*)d_in[10];
    const float* W2    = (const float*)d_in[11];
    const float* al2   = (const float*)d_in[12];
    const float* ar2   = (const float*)d_in[13];
    const float* b2    = (const float*)d_in[14];
    const float* Wres2 = (const float*)d_in[15];

    const int N = in_sizes[0] / 256;  // 50000
    const int E = in_sizes[1];        // 800000

    // workspace layout (fp32 elements)
    float* ws = (float*)d_ws;
    float* H  = ws;                        // [N,128]
    float* A  = H + (size_t)N * 128;       // [N,128]
    float* B  = A + (size_t)N * 128;       // [N,128]
    float* el = B + (size_t)N * 128;       // [N,2]
    float* er = el + (size_t)N * 2;        // [N,2]
    int* deg    = (int*)(er + (size_t)N * 2);
    int* offs   = deg + N;
    int* cursor = offs + N;
    int* incl   = cursor + N;
    int* bsums  = incl + N;                // 256 ints
    int* ssrc   = bsums + 256;             // [E]

    // ---- CSR-by-destination build ----
    hipMemsetAsync(deg, 0, (size_t)N * sizeof(int), stream);
    hipMemsetAsync(cursor, 0, (size_t)N * sizeof(int), stream);
    hist_k<<<(E + 255) / 256, 256, 0, stream>>>(edst, E, deg);
    int nb = (N + 511) / 512;  // 98 <= 128
    scan1_k<<<nb, 512, 0, stream>>>(deg, N, incl, bsums);
    scan2_k<<<1, 128, 0, stream>>>(bsums, nb);
    scan3_k<<<(N + 255) / 256, 256, 0, stream>>>(incl, deg, bsums, offs, N);
    scatter_k<<<(E + 255) / 256, 256, 0, stream>>>(esrc, edst, E, offs, cursor, ssrc);

    int gblk = (N + 63) / 64;   // 782
    int ablk = (N + 3) / 4;     // wave per node, 4 per block

    // ---- Layer 0: IN=256 -> [N,2,64], ELU ----
    gemm_t<256, 128><<<gblk, 256, 0, stream>>>(x, W0, H, N, al0, ar0, el, er);
    agg_v<64, false><<<ablk, 256, 0, stream>>>(ssrc, offs, deg, H, el, er, b0,
                                               nullptr, A, 1, N);

    // ---- Layer 1: 128 -> [N,2,64], identity residual, ELU ----
    gemm_t<128, 128><<<gblk, 256, 0, stream>>>(A, W1, H, N, al1, ar1, el, er);
    agg_v<64, false><<<ablk, 256, 0, stream>>>(ssrc, offs, deg, H, el, er, b1,
                                               A, B, 1, N);

    // ---- Layer 2: 128 -> [N,2,32], projected residual, head-mean ----
    float* h2   = H;                   // [N,64]
    float* hres = H + (size_t)N * 64;  // [N,64]
    gemm_t<128, 64><<<gblk, 256, 0, stream>>>(B, W2, h2, N, al2, ar2, el, er);
    gemm_t<128, 64><<<gblk, 256, 0, stream>>>(B, Wres2, hres, N, nullptr, nullptr,
                                              nullptr, nullptr);
    agg_v<32, true><<<ablk, 256, 0, stream>>>(ssrc, offs, deg, h2, el, er, b2,
                                              hres, (float*)d_out, 0, N);
}